// Round 4
// baseline (328.466 us; speedup 1.0000x reference)
//
#include <hip/hip_runtime.h>

// CTC loss forward (loss only), matching torch/jax reference:
//   T=160 timesteps, N=64 batch, C=6625 classes (blank=0), S=25 max target len
//   L = 2S+1 = 51 extended states; alpha recursion in log-space, NEG=-1e5 sentinel.
// Output: scalar mean_n( -ll_n / len_n ).

constexpr int Tt = 160;
constexpr int Nn = 64;
constexpr int Cc = 6625;
constexpr int Ss = 25;
constexpr int Ll = 2 * Ss + 1;   // 51
constexpr float NEGV = -1e5f;

// Block n handles batch element n.
// Phase 1: 256 threads gather T x 26 emissions (blank + 25 labels) into LDS.
// Phase 2: wave 0, lane l = state l, sequential over t with shfl-up recursion.
__global__ __launch_bounds__(256) void ctc_alpha_kernel(
    const float* __restrict__ x,        // [T, N, C] log-probs
    const int* __restrict__ labels,     // [N, S], values in [1, C-1]
    const int* __restrict__ seqlen,     // [N], values in [5, S]
    float* __restrict__ partial)        // [N] per-batch loss/len
{
    const int n   = blockIdx.x;
    const int tid = threadIdx.x;

    __shared__ int   clsS[32];          // clsS[0]=blank, clsS[1..25]=labels
    __shared__ float eC[Tt][26];        // eC[t][j] = x[t][n][clsS[j]]

    if (tid < 26) {
        clsS[tid] = (tid == 0) ? 0 : labels[n * Ss + (tid - 1)];
    }
    __syncthreads();

    // ---------- Phase 1: gather (4160 scattered fp32 loads, all independent) ----
    const float* xb = x + (size_t)n * Cc;      // x[t][n][c] at xb[t*N*C + c]
    constexpr int TOTAL = Tt * 26;             // 4160
    constexpr int ITERS = (TOTAL + 255) / 256; // 17
    float vals[ITERS];
    #pragma unroll
    for (int it = 0; it < ITERS; ++it) {
        int i = tid + it * 256;
        if (i < TOTAL) {
            int t = i / 26;
            int j = i - t * 26;
            vals[it] = xb[(size_t)t * (Nn * Cc) + clsS[j]];
        }
    }
    #pragma unroll
    for (int it = 0; it < ITERS; ++it) {
        int i = tid + it * 256;
        if (i < TOTAL) {
            int t = i / 26;
            int j = i - t * 26;
            eC[t][j] = vals[it];
        }
    }
    __syncthreads();

    // ---------- Phase 2: alpha recursion on wave 0 ------------------------------
    if (tid >= 64) return;
    const int l = tid;                  // state index; lanes 51..63 are padding

    // emission column for this state: even -> blank(0), odd -> label (l>>1)
    int jj = (l & 1) ? (1 + (l >> 1)) : 0;
    if (jj > 25) jj = 0;                // padding lanes read blank (harmless)

    // can_skip: l odd, l>=3, ext[l] != ext[l-2]
    bool can_skip = false;
    if ((l & 1) && l >= 3 && jj >= 2) {
        can_skip = (clsS[jj] != clsS[jj - 1]);
    }

    // init: alpha0[0]=e0[0], alpha0[1]=e0[1], else NEG
    float alpha = (l <= 1) ? eC[0][jj] : NEGV;

    float e_next = eC[1][jj];
    for (int t = 1; t < Tt; ++t) {
        float e = e_next;
        int tn = (t + 1 < Tt) ? (t + 1) : (Tt - 1);
        e_next = eC[tn][jj];            // prefetch; independent of alpha chain

        float s1 = __shfl_up(alpha, 1);
        float s2 = __shfl_up(alpha, 2);
        if (l < 1) s1 = NEGV;
        if (l < 2 || !can_skip) s2 = NEGV;

        // fused 3-way logaddexp; m is the max so all exp args <= 0
        float m = fmaxf(fmaxf(alpha, s1), s2);
        float sum = __expf(alpha - m) + __expf(s1 - m) + __expf(s2 - m);
        alpha = m + __logf(sum) + e;
    }

    const int len  = seqlen[n];
    const int last = 2 * len;           // final blank; last-1 = final label
    float aL   = __shfl(alpha, last);
    float aLm1 = __shfl(alpha, last - 1);
    if (l == 0) {
        float m  = fmaxf(aL, aLm1);
        float ll = m + log1pf(__expf(-fabsf(aL - aLm1)));
        partial[n] = -ll / (float)len;
    }
}

__global__ void ctc_reduce_kernel(const float* __restrict__ partial,
                                  float* __restrict__ out)
{
    float v = partial[threadIdx.x];     // 64 threads, one wave
    #pragma unroll
    for (int off = 32; off > 0; off >>= 1) v += __shfl_down(v, off);
    if (threadIdx.x == 0) out[0] = v * (1.0f / Nn);
}

extern "C" void kernel_launch(void* const* d_in, const int* in_sizes, int n_in,
                              void* d_out, int out_size, void* d_ws, size_t ws_size,
                              hipStream_t stream) {
    const float* x      = (const float*)d_in[0];
    const int*   labels = (const int*)d_in[1];
    const int*   seqlen = (const int*)d_in[2];
    float* out     = (float*)d_out;
    float* partial = (float*)d_ws;      // 64 floats of scratch

    ctc_alpha_kernel<<<Nn, 256, 0, stream>>>(x, labels, seqlen, partial);
    ctc_reduce_kernel<<<1, 64, 0, stream>>>(partial, out);
}

// Round 5
// 321.554 us; speedup vs baseline: 1.0215x; 1.0215x over previous
//
#include <hip/hip_runtime.h>

// CTC loss forward (loss only), matching torch/jax reference:
//   T=160 timesteps, N=64 batch, C=6625 classes (blank=0), S=25 max target len
//   L = 2S+1 = 51 extended states; alpha recursion in log-space, NEG=-1e5 sentinel.
// Output: scalar mean_n( -ll_n / len_n ).
//
// Structure (r5): one 64-lane wave per batch element. Lane l = extended state l.
// Each lane gathers its own emission column x[t][n][cls(l)] for all t into a
// fully-unrolled 160-register array (no LDS, no __syncthreads), then runs the
// 159-step recursion with DPP wave_shr:1 neighbor shifts (no ds_bpermute).

constexpr int Tt = 160;
constexpr int Nn = 64;
constexpr int Cc = 6625;
constexpr int Ss = 25;
constexpr float NEGV = -1e5f;

__device__ __forceinline__ float dpp_shr1(float x) {
    // lane i <- lane i-1; lane 0 reads out-of-bounds -> 0 (bound_ctrl), masked by caller
    return __int_as_float(__builtin_amdgcn_update_dpp(
        0, __float_as_int(x), 0x138 /*wave_shr:1*/, 0xF, 0xF, true));
}

__global__ __launch_bounds__(64) void ctc_alpha_kernel(
    const float* __restrict__ x,        // [T, N, C] log-probs
    const int* __restrict__ labels,     // [N, S], values in [1, C-1]
    const int* __restrict__ seqlen,     // [N], values in [5, S]
    float* __restrict__ partial)        // [N] per-batch loss/len
{
    const int n = blockIdx.x;
    const int l = threadIdx.x;          // state index; lanes 51..63 are padding

    // emission class for this state: even -> blank(0), odd -> label[(l>>1)]
    int jj = (l & 1) ? (1 + (l >> 1)) : 0;
    if (jj > Ss) jj = 0;                // padding lanes use blank column (harmless)
    int cls = 0;
    if (jj >= 1) cls = labels[n * Ss + (jj - 1)];

    // can_skip: l odd, l>=3, ext[l] != ext[l-2]  (ext[l-2] = cls of lane l-2)
    int c1 = __builtin_amdgcn_update_dpp(0, cls, 0x138, 0xF, 0xF, true);
    int c2 = __builtin_amdgcn_update_dpp(0, c1,  0x138, 0xF, 0xF, true);
    const bool can_skip = (l & 1) && (l >= 3) && (cls != c2);
    const bool lane_ge1 = (l >= 1);

    // ---------- gather: 160 independent scattered loads into registers ----------
    const size_t strideT = (size_t)Nn * Cc;
    const float* xp = x + (size_t)n * Cc + cls;
    float e[Tt];
    #pragma unroll
    for (int t = 0; t < Tt; ++t) {
        e[t] = xp[(size_t)t * strideT];
    }
    __builtin_amdgcn_sched_barrier(0);  // keep all loads issued before the chain

    // ---------- alpha recursion (log-space), DPP neighbor shifts ----------------
    float alpha = (l <= 1) ? e[0] : NEGV;
    #pragma unroll
    for (int t = 1; t < Tt; ++t) {
        float s1 = dpp_shr1(alpha);
        float s2 = dpp_shr1(s1);
        if (!lane_ge1) s1 = NEGV;
        if (!can_skip) s2 = NEGV;
        // fused 3-way logaddexp; m is the max so all exp args <= 0
        float m = fmaxf(fmaxf(alpha, s1), s2);
        float sum = __expf(alpha - m) + __expf(s1 - m) + __expf(s2 - m);
        alpha = m + __logf(sum) + e[t];
    }

    const int len  = seqlen[n];
    const int last = 2 * len;           // final blank; last-1 = final label
    float aL   = __shfl(alpha, last);
    float aLm1 = __shfl(alpha, last - 1);
    if (l == 0) {
        float m  = fmaxf(aL, aLm1);
        float ll = m + log1pf(__expf(-fabsf(aL - aLm1)));
        partial[n] = -ll / (float)len;
    }
}

__global__ void ctc_reduce_kernel(const float* __restrict__ partial,
                                  float* __restrict__ out)
{
    float v = partial[threadIdx.x];     // 64 threads, one wave
    #pragma unroll
    for (int off = 32; off > 0; off >>= 1) v += __shfl_down(v, off);
    if (threadIdx.x == 0) out[0] = v * (1.0f / Nn);
}

extern "C" void kernel_launch(void* const* d_in, const int* in_sizes, int n_in,
                              void* d_out, int out_size, void* d_ws, size_t ws_size,
                              hipStream_t stream) {
    const float* x      = (const float*)d_in[0];
    const int*   labels = (const int*)d_in[1];
    const int*   seqlen = (const int*)d_in[2];
    float* out     = (float*)d_out;
    float* partial = (float*)d_ws;      // 64 floats of scratch

    ctc_alpha_kernel<<<Nn, 64, 0, stream>>>(x, labels, seqlen, partial);
    ctc_reduce_kernel<<<1, 64, 0, stream>>>(partial, out);
}